// Round 3
// baseline (328.671 us; speedup 1.0000x reference)
//
#include <hip/hip_runtime.h>

// out[b,s,k] = sum_n x[b,s,n] * W[k,n] + bias[k]
// W[k,n] = (W_q[k,n] - zeros[k,n/64]) * scales[k,n/64] * scale2[k] * mask[k,n]
// M = B*S = 8192 (rows of x), N = 4096 (reduction), K = 4096 (out features).

#define M_DIM 8192
#define N_DIM 4096
#define K_DIM 4096
#define NTILE 64  // K-tiles of BK=64

typedef __bf16 bf16;
typedef __attribute__((ext_vector_type(8))) bf16 bf16x8;
typedef __attribute__((ext_vector_type(4))) float f32x4;

// ---------------------------------------------------------------- pre-pass 1
__global__ __launch_bounds__(256) void cvt_x_kernel(const float* __restrict__ x,
                                                    bf16* __restrict__ xb) {
  const long total = (long)M_DIM * N_DIM / 8;
  const long stride = (long)gridDim.x * blockDim.x;
  for (long t = (long)blockIdx.x * blockDim.x + threadIdx.x; t < total; t += stride) {
    const long e = t * 8;
    const float4 v0 = *reinterpret_cast<const float4*>(x + e);
    const float4 v1 = *reinterpret_cast<const float4*>(x + e + 4);
    bf16x8 o;
    o[0] = (bf16)v0.x; o[1] = (bf16)v0.y; o[2] = (bf16)v0.z; o[3] = (bf16)v0.w;
    o[4] = (bf16)v1.x; o[5] = (bf16)v1.y; o[6] = (bf16)v1.z; o[7] = (bf16)v1.w;
    *reinterpret_cast<bf16x8*>(xb + e) = o;
  }
}

// ---------------------------------------------------------------- pre-pass 2
__global__ __launch_bounds__(256) void deq_w_kernel(const int* __restrict__ Wq,
                                                    const float* __restrict__ scales,
                                                    const float* __restrict__ zeros,
                                                    const int* __restrict__ mask,
                                                    const float* __restrict__ scale2,
                                                    bf16* __restrict__ wb) {
  const int total = K_DIM * (N_DIM / 8);
  const int stride = gridDim.x * blockDim.x;
  for (int t = blockIdx.x * blockDim.x + threadIdx.x; t < total; t += stride) {
    const int k = t >> 9;
    const int n0 = (t & 511) << 3;
    const int g = n0 >> 6;
    const float s = scales[(k << 6) + g] * scale2[k];
    const float z = zeros[(k << 6) + g];
    const long base = (long)k * N_DIM + n0;
    const int4 q0 = *reinterpret_cast<const int4*>(Wq + base);
    const int4 q1 = *reinterpret_cast<const int4*>(Wq + base + 4);
    const int4 m0 = *reinterpret_cast<const int4*>(mask + base);
    const int4 m1 = *reinterpret_cast<const int4*>(mask + base + 4);
    bf16x8 o;
    o[0] = (bf16)(((float)q0.x - z) * s * (float)m0.x);
    o[1] = (bf16)(((float)q0.y - z) * s * (float)m0.y);
    o[2] = (bf16)(((float)q0.z - z) * s * (float)m0.z);
    o[3] = (bf16)(((float)q0.w - z) * s * (float)m0.w);
    o[4] = (bf16)(((float)q1.x - z) * s * (float)m1.x);
    o[5] = (bf16)(((float)q1.y - z) * s * (float)m1.y);
    o[6] = (bf16)(((float)q1.z - z) * s * (float)m1.z);
    o[7] = (bf16)(((float)q1.w - z) * s * (float)m1.w);
    *reinterpret_cast<bf16x8*>(wb + base) = o;
  }
}

// ---------------------------------------------------------------- GEMM
// 256x256 tile, BK=64, 8 waves (2M x 4N), 8-phase schedule (T3+T4), 2 K-tiles
// per iteration, double-buffered LDS (128 KiB).
//
// Per buffer (32768 bf16): A-k0 @0, A-k1 @8192, B-k0 @16384, B-k1 @24576
// (each 16 KB = 256 rows x 32 cols bf16). Region layout (T2 swizzle,
// measured 0 conflicts in round 2): logical (row, slot 0..3 of 8 bf16) at
// byte (row>>1)*128 + x*16, x = ((row&1)*4 + slot) ^ ((row>>1)&7).
// global_load_lds writes linearly -> per-lane GLOBAL source is pre-permuted
// by the same involution (both-sides-or-neither).
//
// Phase p of tile T reads exactly the half-region staged at phase p of tile
// T-1. Counted vmcnt(4) at odd phases retires precisely the two half-stages
// the next two phases consume (FIFO ledger in session notes); barrier
// extends to all waves. Never drains to 0 in the main loop.
__device__ inline void gload16(const bf16* g, bf16* l) {
  __builtin_amdgcn_global_load_lds(
      (const __attribute__((address_space(1))) void*)g,
      (__attribute__((address_space(3))) void*)l, 16, 0, 0);
}

#define BARRIER asm volatile("s_barrier" ::: "memory")
#define LGKM0   asm volatile("s_waitcnt lgkmcnt(0)" ::: "memory")
#define VM4     asm volatile("s_waitcnt vmcnt(4)" ::: "memory")
#define VM0     asm volatile("s_waitcnt vmcnt(0)" ::: "memory")
#define SBAR    __builtin_amdgcn_sched_barrier(0)

__global__ __launch_bounds__(512, 2) void gemm_kernel(const bf16* __restrict__ xb,
                                                      const bf16* __restrict__ wb,
                                                      const float* __restrict__ bias,
                                                      float* __restrict__ out) {
  __shared__ bf16 lds[65536];  // 128 KiB

  const int tid = threadIdx.x;
  const int lane = tid & 63;
  const int w = tid >> 6;
  const int wr = w >> 2;  // 0..1  (M half, 128 rows)
  const int wc = w & 3;   // 0..3  (N quarter, 64 cols)

  // T1: bijective XCD swizzle; nwg = 512 % 8 == 0.
  const int gid = blockIdx.x;
  const int swz = ((gid & 7) << 6) | (gid >> 3);
  const int bm = swz & 31;  // 32 M-tiles
  const int bk = swz >> 5;  // 16 K-tiles
  const long m0 = (long)bm * 256;
  const long k0 = (long)bk * 256;

  // Staging source decode (linear LDS byte p -> logical row/col), 2 rounds.
  const bf16 *srcA0, *srcA1, *srcB0, *srcB1;
  {
    const int p0 = w * 1024 + lane * 16;
    const int rp0 = p0 >> 7;
    const int v0 = ((p0 >> 4) & 7) ^ (rp0 & 7);
    const int row0 = rp0 * 2 + (v0 >> 2), col0 = (v0 & 3) * 8;
    const int p1 = 8192 + w * 1024 + lane * 16;
    const int rp1 = p1 >> 7;
    const int v1 = ((p1 >> 4) & 7) ^ (rp1 & 7);
    const int row1 = rp1 * 2 + (v1 >> 2), col1 = (v1 & 3) * 8;
    srcA0 = xb + (m0 + row0) * N_DIM + col0;
    srcA1 = xb + (m0 + row1) * N_DIM + col1;
    srcB0 = wb + (k0 + row0) * N_DIM + col0;
    srcB1 = wb + (k0 + row1) * N_DIM + col1;
  }

  // ds_read fragment bases (elements). Row = quad + (lane&15) + i*16,
  // k-slot = lane>>4; swizzle is i-independent (16 rows = 8 row-pairs).
  const int halfrow = (lane & 15) >> 1;
  const int xsw = (((lane & 1) << 2) | (lane >> 4)) ^ halfrow;
  const int aBase = wr * 4096 + halfrow * 64 + xsw * 8;
  const int bBase = wc * 2048 + halfrow * 64 + xsw * 8;

  f32x4 acc[8][4] = {};
  bf16x8 a[8], b01[2], b23[2];

  auto LD_A = [&](int bufbase, int kk) {
#pragma unroll
    for (int mi = 0; mi < 8; ++mi)
      a[mi] = *reinterpret_cast<const bf16x8*>(lds + bufbase + kk * 8192 + aBase + mi * 512);
  };
  auto LD_B = [&](bf16x8* b, int bufbase, int kk, int nh) {
#pragma unroll
    for (int j = 0; j < 2; ++j)
      b[j] = *reinterpret_cast<const bf16x8*>(lds + bufbase + 16384 + kk * 8192 + bBase + (nh * 2 + j) * 512);
  };
  auto MFMA8x2 = [&](bf16x8* b, int nh) {
    __builtin_amdgcn_s_setprio(1);
#pragma unroll
    for (int mi = 0; mi < 8; ++mi)
#pragma unroll
      for (int j = 0; j < 2; ++j)
        acc[mi][nh * 2 + j] = __builtin_amdgcn_mfma_f32_16x16x32_bf16(
            a[mi], b[j], acc[mi][nh * 2 + j], 0, 0, 0);
    __builtin_amdgcn_s_setprio(0);
  };
  auto STAGE2 = [&](const bf16* s0, const bf16* s1, int dstoff) {
    gload16(s0, lds + dstoff + w * 512);
    gload16(s1, lds + dstoff + 4096 + w * 512);
  };

  // Prologue: tile 0 into buf0; order A-k0, B-k0, A-k1, B-k1 (FIFO matters).
  STAGE2(srcA0, srcA1, 0);
  STAGE2(srcB0, srcB1, 16384);
  STAGE2(srcA0 + 32, srcA1 + 32, 8192);
  STAGE2(srcB0 + 32, srcB1 + 32, 24576);
  VM4;  // A-k0,B-k0 landed (this wave); barrier -> all waves
  BARRIER;

  for (int tp = 0; tp < NTILE / 2; ++tp) {
    const int koA = (2 * tp + 1) * 64;  // stage tile 2tp+1 (into buf1)
    const int koB = (2 * tp + 2) * 64;  // stage tile 2tp+2 (into buf0)
    const bool st = (tp < NTILE / 2 - 1);

    // ---- tile 2tp (buf0), staging tile 2tp+1 -> buf1
    // ph0: compute kk0 x ni{0,1}; stage A-k0'
    LD_A(0, 0); LD_B(b01, 0, 0, 0);
    STAGE2(srcA0 + koA, srcA1 + koA, 32768 + 0);
    BARRIER; LGKM0; SBAR;
    MFMA8x2(b01, 0); SBAR;
    BARRIER;
    // ph1: compute kk0 x ni{2,3}; stage B-k0'
    LD_B(b23, 0, 0, 1);
    STAGE2(srcB0 + koA, srcB1 + koA, 32768 + 16384);
    VM4; BARRIER; LGKM0; SBAR;
    MFMA8x2(b23, 1); SBAR;
    BARRIER;
    // ph2: compute kk1 x ni{0,1}; stage A-k1'
    LD_A(0, 1); LD_B(b01, 0, 1, 0);
    STAGE2(srcA0 + koA + 32, srcA1 + koA + 32, 32768 + 8192);
    BARRIER; LGKM0; SBAR;
    MFMA8x2(b01, 0); SBAR;
    BARRIER;
    // ph3: compute kk1 x ni{2,3}; stage B-k1'
    LD_B(b23, 0, 1, 1);
    STAGE2(srcB0 + koA + 32, srcB1 + koA + 32, 32768 + 24576);
    VM4; BARRIER; LGKM0; SBAR;
    MFMA8x2(b23, 1); SBAR;
    BARRIER;

    // ---- tile 2tp+1 (buf1), staging tile 2tp+2 -> buf0 (guarded)
    // ph4
    LD_A(32768, 0); LD_B(b01, 32768, 0, 0);
    if (st) STAGE2(srcA0 + koB, srcA1 + koB, 0);
    BARRIER; LGKM0; SBAR;
    MFMA8x2(b01, 0); SBAR;
    BARRIER;
    // ph5
    LD_B(b23, 32768, 0, 1);
    if (st) STAGE2(srcB0 + koB, srcB1 + koB, 16384);
    if (st) { VM4; } else { VM0; }
    BARRIER; LGKM0; SBAR;
    MFMA8x2(b23, 1); SBAR;
    BARRIER;
    // ph6
    LD_A(32768, 1); LD_B(b01, 32768, 1, 0);
    if (st) STAGE2(srcA0 + koB + 32, srcA1 + koB + 32, 8192);
    BARRIER; LGKM0; SBAR;
    MFMA8x2(b01, 0); SBAR;
    BARRIER;
    // ph7
    LD_B(b23, 32768, 1, 1);
    if (st) STAGE2(srcB0 + koB + 32, srcB1 + koB + 32, 24576);
    if (st) { VM4; } else { VM0; }
    BARRIER; LGKM0; SBAR;
    MFMA8x2(b23, 1); SBAR;
    BARRIER;
  }

  // Epilogue. C/D: col = lane&15 (K-dim), row = (lane>>4)*4 + r (M-dim).
  const int ocol0 = (int)k0 + wc * 64 + (lane & 15);
  const int orow0 = (int)m0 + wr * 128 + (lane >> 4) * 4;
#pragma unroll
  for (int ni = 0; ni < 4; ++ni) {
    const float bv = bias[ocol0 + ni * 16];
#pragma unroll
    for (int mi = 0; mi < 8; ++mi)
#pragma unroll
      for (int r = 0; r < 4; ++r)
        out[(long)(orow0 + mi * 16 + r) * K_DIM + ocol0 + ni * 16] =
            acc[mi][ni][r] + bv;
  }
}

// ---------------------------------------------------------------- launch
extern "C" void kernel_launch(void* const* d_in, const int* in_sizes, int n_in,
                              void* d_out, int out_size, void* d_ws, size_t ws_size,
                              hipStream_t stream) {
  const float* x      = (const float*)d_in[0];
  const int*   Wq     = (const int*)d_in[1];
  const float* scales = (const float*)d_in[2];
  const float* zeros  = (const float*)d_in[3];
  const int*   mask   = (const int*)d_in[4];
  const float* scale2 = (const float*)d_in[5];
  const float* bias   = (const float*)d_in[6];
  float* out = (float*)d_out;

  bf16* xb = (bf16*)d_ws;
  bf16* wb = (bf16*)((char*)d_ws + (size_t)M_DIM * N_DIM * 2);

  cvt_x_kernel<<<2048, 256, 0, stream>>>(x, xb);
  deq_w_kernel<<<2048, 256, 0, stream>>>(Wq, scales, zeros, mask, scale2, wb);

  // Grid: (M/256) * (K/256) = 32 * 16 = 512 blocks, 512 threads.
  gemm_kernel<<<512, 512, 0, stream>>>(xb, wb, bias, out);
}